// Round 6
// baseline (19.281 us; speedup 1.0000x reference)
//
#include <hip/hip_runtime.h>
#include <math.h>

#define DGROUPS 64
#define NG      256
#define DIM     512
#define LPAR    8
#define KNEG    32
#define PPAIRS  (DGROUPS - LPAR)        // 56
#define NCHUNKS 16
#define CHUNK   (NG / NCHUNKS)          // 16 rows per sum-block
#define KSPLIT  8
#define KS      (KNEG / KSPLIT)         // 4 rows per neg-partial block
#define CEPS    1e-8f
#define INV_T   10.0f                   // 1 / TEMP

#define NB_NEG  (PPAIRS * KSPLIT)       // 448 neg-partial blocks (scheduled FIRST)
#define NB_A    (DGROUPS * NCHUNKS)     // 1024 sum blocks
#define NB_K1   (NB_NEG + NB_A)         // 1472

// ws layout (floats):
//   [0, NB_A*DIM)               A partials [1024][DIM]               (2 MB)
//   [WS_NEGP, +56*8*3*512)      neg partials [p][s][{ab,aa,bb}][DIM] (2.6 MB)
//   [WS_LOSS, +64)              loss[p]
//   [WS_CTR,  +16)              int counters: [0]=ticket (zeroed by K1)
#define WS_NEGP (NB_A * DIM)
#define WS_LOSS (WS_NEGP + PPAIRS * KSPLIT * 3 * DIM)
#define WS_CTR  (WS_LOSS + 64)

__device__ __forceinline__ void f4acc(float4& a, const float4 v) {
    a.x += v.x; a.y += v.y; a.z += v.z; a.w += v.w;
}

// ---------------- K1: neg-partials (first) + embs partial sums ----------------
__global__ void __launch_bounds__(128, 4)
k1(const float* __restrict__ embs,
   const float* __restrict__ g1, const float* __restrict__ g2,
   const int* __restrict__ neg1, const int* __restrict__ neg2,
   float* __restrict__ ws) {
    const int b = blockIdx.x;
    const int t = threadIdx.x;                 // 0..127 (float4 lane over DIM)

    if (b < NB_NEG) {
        // ---- neg partial: pair p, k-rows [s*KS, s*KS+KS) ----
        const int p = b >> 3;
        const int s = b & 7;
        if (b == 0 && t == 0) {                // zero K2's ticket counter
            ((int*)(ws + WS_CTR))[0] = 0;
        }
        __shared__ int i1[KS], i2[KS];
        if (t < KS)           i1[t] = neg1[p * KNEG + s * KS + t];
        else if (t < 2 * KS)  i2[t - KS] = neg2[p * KNEG + s * KS + (t - KS)];
        __syncthreads();

        float4 sab = make_float4(0.f,0.f,0.f,0.f);
        float4 saa = make_float4(0.f,0.f,0.f,0.f);
        float4 sbb = make_float4(0.f,0.f,0.f,0.f);
        #pragma unroll
        for (int k = 0; k < KS; ++k) {
            float4 a  = ((const float4*)g1)[(size_t)i1[k] * (DIM/4) + t];
            float4 bb = ((const float4*)g2)[(size_t)i2[k] * (DIM/4) + t];
            sab.x += a.x*bb.x; sab.y += a.y*bb.y; sab.z += a.z*bb.z; sab.w += a.w*bb.w;
            saa.x += a.x*a.x;  saa.y += a.y*a.y;  saa.z += a.z*a.z;  saa.w += a.w*a.w;
            sbb.x += bb.x*bb.x; sbb.y += bb.y*bb.y; sbb.z += bb.z*bb.z; sbb.w += bb.w*bb.w;
        }
        float4* dst = (float4*)(ws + WS_NEGP + (size_t)((p * KSPLIT + s) * 3) * DIM);
        dst[t]                 = sab;
        dst[t +     (DIM/4)]   = saa;
        dst[t + 2 * (DIM/4)]   = sbb;
    } else {
        // ---- embs partial sum: group d, rows [c*CHUNK, c*CHUNK+CHUNK) ----
        const int ab = b - NB_NEG;
        const int d = ab >> 4;
        const int c = ab & 15;
        const float4* src = (const float4*)(embs + (size_t)d * NG * DIM);
        float4 acc = make_float4(0.f, 0.f, 0.f, 0.f);
        int idx = (c * CHUNK) * (DIM / 4) + t;
        #pragma unroll
        for (int n = 0; n < CHUNK; ++n) { f4acc(acc, src[idx]); idx += DIM / 4; }
        ((float4*)(ws + (size_t)ab * DIM))[t] = acc;
    }
}

// ---------------- K2: combine neg partials + pos cosine + loss + final ----------------
__global__ void __launch_bounds__(128, 4)
k2(const float* __restrict__ ws_ro, float* __restrict__ ws, float* __restrict__ out) {
    const int p = blockIdx.x;
    const int t = threadIdx.x;

    // ---- combine neg partials, per-dim cosine, exp-sum ----
    float4 sab = make_float4(0.f,0.f,0.f,0.f);
    float4 saa = make_float4(0.f,0.f,0.f,0.f);
    float4 sbb = make_float4(0.f,0.f,0.f,0.f);
    #pragma unroll
    for (int s = 0; s < KSPLIT; ++s) {
        const float4* src = (const float4*)(ws_ro + WS_NEGP + (size_t)((p * KSPLIT + s) * 3) * DIM);
        f4acc(sab, src[t]);
        f4acc(saa, src[t +     (DIM/4)]);
        f4acc(sbb, src[t + 2 * (DIM/4)]);
    }
    float e =
        expf(INV_T * sab.x / (fmaxf(sqrtf(saa.x), CEPS) * fmaxf(sqrtf(sbb.x), CEPS))) +
        expf(INV_T * sab.y / (fmaxf(sqrtf(saa.y), CEPS) * fmaxf(sqrtf(sbb.y), CEPS))) +
        expf(INV_T * sab.z / (fmaxf(sqrtf(saa.z), CEPS) * fmaxf(sqrtf(sbb.z), CEPS))) +
        expf(INV_T * sab.w / (fmaxf(sqrtf(saa.w), CEPS) * fmaxf(sqrtf(sbb.w), CEPS)));
    #pragma unroll
    for (int off = 32; off >= 1; off >>= 1)
        e += __shfl_down(e, off, 64);
    __shared__ float redE[2];
    if ((t & 63) == 0) redE[t >> 6] = e;
    __syncthreads();
    const float en_total = redE[0] + redE[1];

    // ---- pos cosine from A partials ----
    float4 si = make_float4(0.f,0.f,0.f,0.f);
    float4 sj = make_float4(0.f,0.f,0.f,0.f);
    #pragma unroll
    for (int c = 0; c < NCHUNKS; ++c) {
        f4acc(si, ((const float4*)ws_ro)[(size_t)(p * NCHUNKS + c) * (DIM/4) + t]);
        f4acc(sj, ((const float4*)ws_ro)[(size_t)((p + LPAR) * NCHUNKS + c) * (DIM/4) + t]);
    }
    float dot = si.x*sj.x + si.y*sj.y + si.z*sj.z + si.w*sj.w;
    float na  = si.x*si.x + si.y*si.y + si.z*si.z + si.w*si.w;
    float nb  = sj.x*sj.x + sj.y*sj.y + sj.z*sj.z + sj.w*sj.w;
    #pragma unroll
    for (int off = 32; off >= 1; off >>= 1) {
        dot += __shfl_down(dot, off, 64);
        na  += __shfl_down(na,  off, 64);
        nb  += __shfl_down(nb,  off, 64);
    }
    __shared__ float red[3][2];
    __shared__ int is_last;
    if ((t & 63) == 0) { red[0][t>>6] = dot; red[1][t>>6] = na; red[2][t>>6] = nb; }
    if (t == 0) is_last = 0;
    __syncthreads();

    if (t == 0) {
        float dd = red[0][0] + red[0][1];
        float aa = red[1][0] + red[1][1];
        float bb = red[2][0] + red[2][1];
        float pos = dd / (fmaxf(sqrtf(aa), CEPS) * fmaxf(sqrtf(bb), CEPS));
        float pp  = pos * INV_T;
        float loss = logf(expf(pp) + en_total) - pp;      // -log(num/den)
        __hip_atomic_store(&ws[WS_LOSS + p], loss,
                           __ATOMIC_RELEASE, __HIP_MEMORY_SCOPE_AGENT);
        int tk = __hip_atomic_fetch_add((int*)(ws + WS_CTR), 1,
                                        __ATOMIC_ACQ_REL, __HIP_MEMORY_SCOPE_AGENT);
        if (tk == PPAIRS - 1) is_last = 1;
    }
    __syncthreads();

    if (is_last) {
        float l = 0.f;
        if (t < PPAIRS)
            l = __hip_atomic_load(&ws[WS_LOSS + t],
                                  __ATOMIC_ACQUIRE, __HIP_MEMORY_SCOPE_AGENT);
        if (t < 64) {
            #pragma unroll
            for (int off = 32; off >= 1; off >>= 1)
                l += __shfl_down(l, off, 64);
            if (t == 0) out[0] = 2.0f * l;
        }
    }
}

extern "C" void kernel_launch(void* const* d_in, const int* in_sizes, int n_in,
                              void* d_out, int out_size, void* d_ws, size_t ws_size,
                              hipStream_t stream) {
    const float* embs = (const float*)d_in[0];
    // d_in[1] = g0 (dead on this output path)
    const float* g1   = (const float*)d_in[2];
    const float* g2   = (const float*)d_in[3];
    const int*   neg1 = (const int*)d_in[4];
    const int*   neg2 = (const int*)d_in[5];
    float* ws  = (float*)d_ws;
    float* out = (float*)d_out;

    k1<<<NB_K1, 128, 0, stream>>>(embs, g1, g2, neg1, neg2, ws);
    k2<<<PPAIRS, 128, 0, stream>>>(ws, ws, out);
}

// Round 7
// 17.823 us; speedup vs baseline: 1.0818x; 1.0818x over previous
//
#include <hip/hip_runtime.h>
#include <math.h>

#define DGROUPS 64
#define NG      256
#define DIM     512
#define LPAR    8
#define KNEG    32
#define PPAIRS  (DGROUPS - LPAR)        // 56
#define NCHUNKS 8
#define CHUNK   (NG / NCHUNKS)          // 32 rows per sum-block
#define KSPLIT  4
#define KS      (KNEG / KSPLIT)         // 8 rows per neg-partial block
#define CEPS    1e-8f
#define INV_T   10.0f                   // 1 / TEMP

#define NB_NEG  (PPAIRS * KSPLIT)       // 224 neg-partial blocks (scheduled FIRST)
#define NB_A    (DGROUPS * NCHUNKS)     // 512 sum blocks
#define NB_K1   (NB_NEG + NB_A)         // 736

// ws layout (floats):
//   [0, 512*512)                A partials [512][DIM]                (1 MB)
//   [WS_NEGP, +56*4*3*512)      neg partials [p][s][{ab,aa,bb}][DIM] (1.3 MB)
//   [WS_LOSS, +64)              loss[p]
//   [WS_CTR,  +16)              int counters: [0]=ticket (zeroed by K1)
#define WS_NEGP (NB_A * DIM)
#define WS_LOSS (WS_NEGP + PPAIRS * KSPLIT * 3 * DIM)
#define WS_CTR  (WS_LOSS + 64)

__device__ __forceinline__ void f4acc(float4& a, const float4 v) {
    a.x += v.x; a.y += v.y; a.z += v.z; a.w += v.w;
}

// ---------------- K1: neg-partials (first) + embs partial sums ----------------
__global__ void __launch_bounds__(128, 4)
k1(const float* __restrict__ embs,
   const float* __restrict__ g1, const float* __restrict__ g2,
   const int* __restrict__ neg1, const int* __restrict__ neg2,
   float* __restrict__ ws) {
    const int b = blockIdx.x;
    const int t = threadIdx.x;                 // 0..127 (float4 lane over DIM)

    if (b < NB_NEG) {
        // ---- neg partial: pair p, k-rows [s*KS, s*KS+KS) ----
        const int p = b >> 2;
        const int s = b & 3;
        if (b == 0 && t == 0) {                // zero K2's ticket counter
            ((int*)(ws + WS_CTR))[0] = 0;
        }
        __shared__ int i1[KS], i2[KS];
        if (t < KS)           i1[t] = neg1[p * KNEG + s * KS + t];
        else if (t < 2 * KS)  i2[t - KS] = neg2[p * KNEG + s * KS + (t - KS)];
        __syncthreads();

        float4 sab = make_float4(0.f,0.f,0.f,0.f);
        float4 saa = make_float4(0.f,0.f,0.f,0.f);
        float4 sbb = make_float4(0.f,0.f,0.f,0.f);
        #pragma unroll
        for (int k = 0; k < KS; ++k) {
            float4 a  = ((const float4*)g1)[(size_t)i1[k] * (DIM/4) + t];
            float4 bb = ((const float4*)g2)[(size_t)i2[k] * (DIM/4) + t];
            sab.x += a.x*bb.x; sab.y += a.y*bb.y; sab.z += a.z*bb.z; sab.w += a.w*bb.w;
            saa.x += a.x*a.x;  saa.y += a.y*a.y;  saa.z += a.z*a.z;  saa.w += a.w*a.w;
            sbb.x += bb.x*bb.x; sbb.y += bb.y*bb.y; sbb.z += bb.z*bb.z; sbb.w += bb.w*bb.w;
        }
        float4* dst = (float4*)(ws + WS_NEGP + (size_t)((p * KSPLIT + s) * 3) * DIM);
        dst[t]                 = sab;
        dst[t +     (DIM/4)]   = saa;
        dst[t + 2 * (DIM/4)]   = sbb;
    } else {
        // ---- embs partial sum: group d, rows [c*CHUNK, c*CHUNK+CHUNK) ----
        const int ab = b - NB_NEG;
        const int d = ab >> 3;
        const int c = ab & 7;
        const float4* src = (const float4*)(embs + (size_t)d * NG * DIM);
        float4 acc = make_float4(0.f, 0.f, 0.f, 0.f);
        int idx = (c * CHUNK) * (DIM / 4) + t;
        #pragma unroll 8
        for (int n = 0; n < CHUNK; ++n) { f4acc(acc, src[idx]); idx += DIM / 4; }
        ((float4*)(ws + (size_t)ab * DIM))[t] = acc;
    }
}

// ---------------- K2: combine neg partials + pos cosine + loss + final ----------------
__global__ void __launch_bounds__(128, 4)
k2(const float* __restrict__ ws_ro, float* __restrict__ ws, float* __restrict__ out) {
    const int p = blockIdx.x;
    const int t = threadIdx.x;

    // ---- combine neg partials, per-dim cosine, exp-sum ----
    float4 sab = make_float4(0.f,0.f,0.f,0.f);
    float4 saa = make_float4(0.f,0.f,0.f,0.f);
    float4 sbb = make_float4(0.f,0.f,0.f,0.f);
    #pragma unroll
    for (int s = 0; s < KSPLIT; ++s) {
        const float4* src = (const float4*)(ws_ro + WS_NEGP + (size_t)((p * KSPLIT + s) * 3) * DIM);
        f4acc(sab, src[t]);
        f4acc(saa, src[t +     (DIM/4)]);
        f4acc(sbb, src[t + 2 * (DIM/4)]);
    }
    float e =
        expf(INV_T * sab.x / (fmaxf(sqrtf(saa.x), CEPS) * fmaxf(sqrtf(sbb.x), CEPS))) +
        expf(INV_T * sab.y / (fmaxf(sqrtf(saa.y), CEPS) * fmaxf(sqrtf(sbb.y), CEPS))) +
        expf(INV_T * sab.z / (fmaxf(sqrtf(saa.z), CEPS) * fmaxf(sqrtf(sbb.z), CEPS))) +
        expf(INV_T * sab.w / (fmaxf(sqrtf(saa.w), CEPS) * fmaxf(sqrtf(sbb.w), CEPS)));
    #pragma unroll
    for (int off = 32; off >= 1; off >>= 1)
        e += __shfl_down(e, off, 64);
    __shared__ float redE[2];
    if ((t & 63) == 0) redE[t >> 6] = e;
    __syncthreads();
    const float en_total = redE[0] + redE[1];

    // ---- pos cosine from A partials ----
    float4 si = make_float4(0.f,0.f,0.f,0.f);
    float4 sj = make_float4(0.f,0.f,0.f,0.f);
    #pragma unroll
    for (int c = 0; c < NCHUNKS; ++c) {
        f4acc(si, ((const float4*)ws_ro)[(size_t)(p * NCHUNKS + c) * (DIM/4) + t]);
        f4acc(sj, ((const float4*)ws_ro)[(size_t)((p + LPAR) * NCHUNKS + c) * (DIM/4) + t]);
    }
    float dot = si.x*sj.x + si.y*sj.y + si.z*sj.z + si.w*sj.w;
    float na  = si.x*si.x + si.y*si.y + si.z*si.z + si.w*si.w;
    float nb  = sj.x*sj.x + sj.y*sj.y + sj.z*sj.z + sj.w*sj.w;
    #pragma unroll
    for (int off = 32; off >= 1; off >>= 1) {
        dot += __shfl_down(dot, off, 64);
        na  += __shfl_down(na,  off, 64);
        nb  += __shfl_down(nb,  off, 64);
    }
    __shared__ float red[3][2];
    __shared__ int is_last;
    if ((t & 63) == 0) { red[0][t>>6] = dot; red[1][t>>6] = na; red[2][t>>6] = nb; }
    if (t == 0) is_last = 0;
    __syncthreads();

    if (t == 0) {
        float dd = red[0][0] + red[0][1];
        float aa = red[1][0] + red[1][1];
        float bb = red[2][0] + red[2][1];
        float pos = dd / (fmaxf(sqrtf(aa), CEPS) * fmaxf(sqrtf(bb), CEPS));
        float pp  = pos * INV_T;
        float loss = logf(expf(pp) + en_total) - pp;      // -log(num/den)
        __hip_atomic_store(&ws[WS_LOSS + p], loss,
                           __ATOMIC_RELEASE, __HIP_MEMORY_SCOPE_AGENT);
        int tk = __hip_atomic_fetch_add((int*)(ws + WS_CTR), 1,
                                        __ATOMIC_ACQ_REL, __HIP_MEMORY_SCOPE_AGENT);
        if (tk == PPAIRS - 1) is_last = 1;
    }
    __syncthreads();

    if (is_last) {
        float l = 0.f;
        if (t < PPAIRS)
            l = __hip_atomic_load(&ws[WS_LOSS + t],
                                  __ATOMIC_ACQUIRE, __HIP_MEMORY_SCOPE_AGENT);
        if (t < 64) {
            #pragma unroll
            for (int off = 32; off >= 1; off >>= 1)
                l += __shfl_down(l, off, 64);
            if (t == 0) out[0] = 2.0f * l;
        }
    }
}

extern "C" void kernel_launch(void* const* d_in, const int* in_sizes, int n_in,
                              void* d_out, int out_size, void* d_ws, size_t ws_size,
                              hipStream_t stream) {
    const float* embs = (const float*)d_in[0];
    // d_in[1] = g0 (dead on this output path)
    const float* g1   = (const float*)d_in[2];
    const float* g2   = (const float*)d_in[3];
    const int*   neg1 = (const int*)d_in[4];
    const int*   neg2 = (const int*)d_in[5];
    float* ws  = (float*)d_ws;
    float* out = (float*)d_out;

    k1<<<NB_K1, 128, 0, stream>>>(embs, g1, g2, neg1, neg2, ws);
    k2<<<PPAIRS, 128, 0, stream>>>(ws, ws, out);
}